// Round 2
// baseline (606.012 us; speedup 1.0000x reference)
//
#include <hip/hip_runtime.h>

#define B_N 2048
#define T_N 512
#define D_N 88
#define H_N 16
#define NEGF (-1e30f)
#define LN2F 0.69314718055994530942f

// ---------- DPP helpers (row_ror within 16-lane rows) ----------
template<int CTRL>
__device__ __forceinline__ float dppf(float x) {
    return __int_as_float(__builtin_amdgcn_update_dpp(
        0, __float_as_int(x), CTRL, 0xF, 0xF, false));
}

// full 16-lane rotate-reduce max (uniform result across the 16-group)
__device__ __forceinline__ float grp16_max(float v) {
    v = fmaxf(v, dppf<0x128>(v)); // ror8
    v = fmaxf(v, dppf<0x124>(v)); // ror4
    v = fmaxf(v, dppf<0x122>(v)); // ror2
    v = fmaxf(v, dppf<0x121>(v)); // ror1
    return v;
}
__device__ __forceinline__ float grp16_sum(float v) {
    v += dppf<0x128>(v);
    v += dppf<0x124>(v);
    v += dppf<0x122>(v);
    v += dppf<0x121>(v);
    return v;
}

// Self-calibrating A gather: aro[j] = A[src_lane_of_ror_j][h], so
// matvec16 computes sum_i p[i]*A[i][h] regardless of ror direction.
__device__ __forceinline__ void calib(const float* __restrict__ px, int h,
                                      float (&aro)[16]) {
    float idxf = (float)h;
    aro[0]  = px[h * 16 + h];
    aro[1]  = px[((int)dppf<0x121>(idxf)) * 16 + h];
    aro[2]  = px[((int)dppf<0x122>(idxf)) * 16 + h];
    aro[3]  = px[((int)dppf<0x123>(idxf)) * 16 + h];
    aro[4]  = px[((int)dppf<0x124>(idxf)) * 16 + h];
    aro[5]  = px[((int)dppf<0x125>(idxf)) * 16 + h];
    aro[6]  = px[((int)dppf<0x126>(idxf)) * 16 + h];
    aro[7]  = px[((int)dppf<0x127>(idxf)) * 16 + h];
    aro[8]  = px[((int)dppf<0x128>(idxf)) * 16 + h];
    aro[9]  = px[((int)dppf<0x129>(idxf)) * 16 + h];
    aro[10] = px[((int)dppf<0x12A>(idxf)) * 16 + h];
    aro[11] = px[((int)dppf<0x12B>(idxf)) * 16 + h];
    aro[12] = px[((int)dppf<0x12C>(idxf)) * 16 + h];
    aro[13] = px[((int)dppf<0x12D>(idxf)) * 16 + h];
    aro[14] = px[((int)dppf<0x12E>(idxf)) * 16 + h];
    aro[15] = px[((int)dppf<0x12F>(idxf)) * 16 + h];
}

__device__ __forceinline__ float matvec16(float p, const float (&aro)[16]) {
    float a0 = p * aro[0];
    float a1 = dppf<0x121>(p) * aro[1];
    float a2 = dppf<0x122>(p) * aro[2];
    float a3 = dppf<0x123>(p) * aro[3];
    a0 += dppf<0x124>(p) * aro[4];
    a1 += dppf<0x125>(p) * aro[5];
    a2 += dppf<0x126>(p) * aro[6];
    a3 += dppf<0x127>(p) * aro[7];
    a0 += dppf<0x128>(p) * aro[8];
    a1 += dppf<0x129>(p) * aro[9];
    a2 += dppf<0x12A>(p) * aro[10];
    a3 += dppf<0x12B>(p) * aro[11];
    a0 += dppf<0x12C>(p) * aro[12];
    a1 += dppf<0x12D>(p) * aro[13];
    a2 += dppf<0x12E>(p) * aro[14];
    a3 += dppf<0x12F>(p) * aro[15];
    return (a0 + a1) + (a2 + a3);
}

// one HMM step in log2 domain, alpha = (aRel <= 0 per lane, group-uniform M)
__device__ __forceinline__ void hmm_step(float& aRel, float& M, float emit2,
                                         bool valid, const float (&aro)[16]) {
    float p = exp2f(aRel);               // v_exp_f32
    float s = matvec16(p, aro);          // sum_i p[i] * A[i][h], linear
    float g = __log2f(s) + emit2;        // candidate new alpha (pre-norm)
    float mg = grp16_max(g);             // group max (uniform in 16-group)
    if (valid) {                         // valid is group-uniform
        aRel = g - mg;
        M    = M + mg;
    }
}

// ---------- kernel 0: weight prep (log2 domain) ----------
__global__ void hmm_prep(const float* __restrict__ probs_y,
                         float* __restrict__ wtab) {
    int tid = threadIdx.x;
    for (int i = tid; i < H_N * D_N; i += 256) {
        float py = probs_y[i];
        wtab[i] = log2f(py) - log2f(1.0f - py);
    }
    if (tid < H_N) {
        float s = 0.0f;
        for (int d = 0; d < D_N; ++d)
            s += log2f(1.0f - probs_y[tid * D_N + d]);
        wtab[H_N * D_N + tid] = s;
    }
}

// ---------- kernel 1: emission, emit[B][H][T] (only t < len) ----------
__global__ __launch_bounds__(256) void hmm_emit(
    const float* __restrict__ seq, const int* __restrict__ lengths,
    const float* __restrict__ wtab, float* __restrict__ emitBuf) {
    int bid = blockIdx.x;
    int b = bid >> 3;
    int t0 = (bid & 7) * 64;
    int len = lengths[b];
    if (t0 >= len) return;                      // uniform early-exit

    __shared__ float sW[H_N * D_N + H_N];       // 1424 floats
    __shared__ float sS[64 * 92];               // 64 rows padded to 92 floats
    int tid = threadIdx.x;

    for (int i = tid; i < H_N * D_N + H_N; i += 256) sW[i] = wtab[i];

    const float4* gs = (const float4*)(seq + ((size_t)b * T_N + t0) * D_N);
    for (int f = tid; f < 64 * 22; f += 256) {
        float4 v = gs[f];
        int row = f / 22, j = f - row * 22;
        *(float4*)(&sS[row * 92 + j * 4]) = v;
    }
    __syncthreads();

    int row = tid & 63, hq = tid >> 6;          // wave w -> hq = w (uniform)
    int t = t0 + row;
    if (t >= len) return;

    const float* srow = &sS[row * 92];
    const float* w0 = &sW[(hq * 4 + 0) * D_N];
    const float* w1 = &sW[(hq * 4 + 1) * D_N];
    const float* w2 = &sW[(hq * 4 + 2) * D_N];
    const float* w3 = &sW[(hq * 4 + 3) * D_N];
    const float* bb = &sW[H_N * D_N];
    float a0 = bb[hq * 4 + 0], a1 = bb[hq * 4 + 1];
    float a2 = bb[hq * 4 + 2], a3 = bb[hq * 4 + 3];
#pragma unroll
    for (int j = 0; j < 22; ++j) {
        float4 sv = *(const float4*)(srow + 4 * j);
        float4 q0 = *(const float4*)(w0 + 4 * j);
        float4 q1 = *(const float4*)(w1 + 4 * j);
        float4 q2 = *(const float4*)(w2 + 4 * j);
        float4 q3 = *(const float4*)(w3 + 4 * j);
        a0 += sv.x * q0.x + sv.y * q0.y + sv.z * q0.z + sv.w * q0.w;
        a1 += sv.x * q1.x + sv.y * q1.y + sv.z * q1.z + sv.w * q1.w;
        a2 += sv.x * q2.x + sv.y * q2.y + sv.z * q2.z + sv.w * q2.w;
        a3 += sv.x * q3.x + sv.y * q3.y + sv.z * q3.z + sv.w * q3.w;
    }
    size_t ob = ((size_t)b * H_N + hq * 4) * T_N + t;
    emitBuf[ob]           = a0;
    emitBuf[ob + T_N]     = a1;
    emitBuf[ob + 2 * T_N] = a2;
    emitBuf[ob + 3 * T_N] = a3;
}

// ---------- kernel 2: forward scan, 1 wave = 4 sequences ----------
__global__ __launch_bounds__(64) void hmm_scan(
    const float* __restrict__ probs_x, const float* __restrict__ emitBuf,
    const int* __restrict__ lengths, const float* __restrict__ scale,
    float* __restrict__ out) {
    int lane = threadIdx.x;
    int sl = lane >> 4, h = lane & 15;
    int b0 = blockIdx.x * 4;
    int b = b0 + sl;
    int len = lengths[b];

    float aro[16];
    calib(probs_x, h, aro);

    // wave-max length via 4 wave-uniform scalar loads (ds_swizzle BitMode
    // cannot cross 32-lane halves — previous xor-32 attempt was QuadMode garbage)
    int wmax = max(max(lengths[b0], lengths[b0 + 1]),
                   max(lengths[b0 + 2], lengths[b0 + 3]));

    const float4* eb = (const float4*)(emitBuf + ((size_t)(b * H_N + h)) * T_N);
    float aRel = (h == 0) ? 0.0f : NEGF;
    float M = 0.0f;

    int nch = (wmax + 3) >> 2;
    float4 cur = eb[0];
    for (int c = 0; c < nch; ++c) {
        float4 nxt;
        if (c + 1 < nch) nxt = eb[c + 1];       // prefetch 4 steps ahead
        int t0c = c * 4;
        hmm_step(aRel, M, cur.x, t0c + 0 < len, aro);
        hmm_step(aRel, M, cur.y, t0c + 1 < len, aro);
        hmm_step(aRel, M, cur.z, t0c + 2 < len, aro);
        hmm_step(aRel, M, cur.w, t0c + 3 < len, aro);
        cur = nxt;
    }
    float pf = exp2f(aRel);
    float s = grp16_sum(pf);
    if (h == 0)
        out[b] = scale[0] * (LN2F * (M + __log2f(s)));
}

// ---------- fallback: fused naive (if ws too small), correct but slow ----------
__global__ __launch_bounds__(64) void hmm_fused_naive(
    const float* __restrict__ seq, const float* __restrict__ px,
    const float* __restrict__ py, const float* __restrict__ sc,
    const int* __restrict__ lengths, float* __restrict__ out) {
    int lane = threadIdx.x;
    int sl = lane >> 4, h = lane & 15;
    int b0 = blockIdx.x * 4;
    int b = b0 + sl;
    int len = lengths[b];

    float aro[16];
    calib(px, h, aro);

    float wreg[88];
    float b2 = 0.0f;
#pragma unroll
    for (int d = 0; d < D_N; ++d) {
        float p = py[h * D_N + d];
        float l1 = log2f(1.0f - p);
        wreg[d] = log2f(p) - l1;
        b2 += l1;
    }
    int wmax = max(max(lengths[b0], lengths[b0 + 1]),
                   max(lengths[b0 + 2], lengths[b0 + 3]));

    float aRel = (h == 0) ? 0.0f : NEGF;
    float M = 0.0f;
    for (int t = 0; t < wmax; ++t) {
        const float4* sp = (const float4*)(seq + ((size_t)b * T_N + t) * D_N);
        float e = b2;
#pragma unroll
        for (int j = 0; j < 22; ++j) {
            float4 v = sp[j];
            e += v.x * wreg[4 * j] + v.y * wreg[4 * j + 1] +
                 v.z * wreg[4 * j + 2] + v.w * wreg[4 * j + 3];
        }
        hmm_step(aRel, M, e, t < len, aro);
    }
    float pf = exp2f(aRel);
    float s = grp16_sum(pf);
    if (h == 0)
        out[b] = sc[0] * (LN2F * (M + __log2f(s)));
}

extern "C" void kernel_launch(void* const* d_in, const int* in_sizes, int n_in,
                              void* d_out, int out_size, void* d_ws,
                              size_t ws_size, hipStream_t stream) {
    const float* seq = (const float*)d_in[0];   // [B,T,D] f32
    const float* px  = (const float*)d_in[1];   // [H,H]   f32 (linear probs)
    const float* py  = (const float*)d_in[2];   // [H,D]   f32
    const float* sc  = (const float*)d_in[3];   // [1]     f32
    const int*   len = (const int*)d_in[4];     // [B]     i32
    float* out = (float*)d_out;                 // [B]     f32

    size_t emit_elems = (size_t)B_N * H_N * T_N;              // 16.7M floats
    size_t need = (emit_elems + (H_N * D_N + H_N)) * sizeof(float);
    if (ws_size >= need) {
        float* emitBuf = (float*)d_ws;
        float* wtab = emitBuf + emit_elems;
        hmm_prep<<<1, 256, 0, stream>>>(py, wtab);
        hmm_emit<<<B_N * 8, 256, 0, stream>>>(seq, len, wtab, emitBuf);
        hmm_scan<<<B_N / 4, 64, 0, stream>>>(px, emitBuf, len, sc, out);
    } else {
        hmm_fused_naive<<<B_N / 4, 64, 0, stream>>>(seq, px, py, sc, len, out);
    }
}

// Round 3
// 545.439 us; speedup vs baseline: 1.1111x; 1.1111x over previous
//
#include <hip/hip_runtime.h>

#define B_N 2048
#define T_N 512
#define D_N 88
#define H_N 16
#define NEGF (-1e30f)
#define LN2F 0.69314718055994530942f

typedef __attribute__((ext_vector_type(8))) short short8;
typedef __attribute__((ext_vector_type(4))) float floatx4;

// ---------- DPP helpers (row_ror within 16-lane rows) ----------
template<int CTRL>
__device__ __forceinline__ float dppf(float x) {
    return __int_as_float(__builtin_amdgcn_update_dpp(
        0, __float_as_int(x), CTRL, 0xF, 0xF, false));
}

__device__ __forceinline__ float grp16_max(float v) {
    v = fmaxf(v, dppf<0x128>(v)); // ror8
    v = fmaxf(v, dppf<0x124>(v)); // ror4
    v = fmaxf(v, dppf<0x122>(v)); // ror2
    v = fmaxf(v, dppf<0x121>(v)); // ror1
    return v;
}
__device__ __forceinline__ float grp16_sum(float v) {
    v += dppf<0x128>(v);
    v += dppf<0x124>(v);
    v += dppf<0x122>(v);
    v += dppf<0x121>(v);
    return v;
}

// Self-calibrating A gather: aro[j] = A[src_lane_of_ror_j][h]
__device__ __forceinline__ void calib(const float* __restrict__ px, int h,
                                      float (&aro)[16]) {
    float idxf = (float)h;
    aro[0]  = px[h * 16 + h];
    aro[1]  = px[((int)dppf<0x121>(idxf)) * 16 + h];
    aro[2]  = px[((int)dppf<0x122>(idxf)) * 16 + h];
    aro[3]  = px[((int)dppf<0x123>(idxf)) * 16 + h];
    aro[4]  = px[((int)dppf<0x124>(idxf)) * 16 + h];
    aro[5]  = px[((int)dppf<0x125>(idxf)) * 16 + h];
    aro[6]  = px[((int)dppf<0x126>(idxf)) * 16 + h];
    aro[7]  = px[((int)dppf<0x127>(idxf)) * 16 + h];
    aro[8]  = px[((int)dppf<0x128>(idxf)) * 16 + h];
    aro[9]  = px[((int)dppf<0x129>(idxf)) * 16 + h];
    aro[10] = px[((int)dppf<0x12A>(idxf)) * 16 + h];
    aro[11] = px[((int)dppf<0x12B>(idxf)) * 16 + h];
    aro[12] = px[((int)dppf<0x12C>(idxf)) * 16 + h];
    aro[13] = px[((int)dppf<0x12D>(idxf)) * 16 + h];
    aro[14] = px[((int)dppf<0x12E>(idxf)) * 16 + h];
    aro[15] = px[((int)dppf<0x12F>(idxf)) * 16 + h];
}

__device__ __forceinline__ float matvec16(float p, const float (&aro)[16]) {
    float a0 = p * aro[0];
    float a1 = dppf<0x121>(p) * aro[1];
    float a2 = dppf<0x122>(p) * aro[2];
    float a3 = dppf<0x123>(p) * aro[3];
    a0 += dppf<0x124>(p) * aro[4];
    a1 += dppf<0x125>(p) * aro[5];
    a2 += dppf<0x126>(p) * aro[6];
    a3 += dppf<0x127>(p) * aro[7];
    a0 += dppf<0x128>(p) * aro[8];
    a1 += dppf<0x129>(p) * aro[9];
    a2 += dppf<0x12A>(p) * aro[10];
    a3 += dppf<0x12B>(p) * aro[11];
    a0 += dppf<0x12C>(p) * aro[12];
    a1 += dppf<0x12D>(p) * aro[13];
    a2 += dppf<0x12E>(p) * aro[14];
    a3 += dppf<0x12F>(p) * aro[15];
    return (a0 + a1) + (a2 + a3);
}

// step with pre-centered emission; renorm handled by caller every 4 steps
__device__ __forceinline__ void scan_step(float& aRel, float& M, float ec,
                                          float cval, bool valid,
                                          const float (&aro)[16]) {
    float p = exp2f(aRel);
    float s = matvec16(p, aro);
    float g = __log2f(s) + ec;
    if (valid) { aRel = g; M += cval; }
}

// old-style step (fallback kernel only)
__device__ __forceinline__ void hmm_step(float& aRel, float& M, float emit2,
                                         bool valid, const float (&aro)[16]) {
    float p = exp2f(aRel);
    float s = matvec16(p, aro);
    float g = __log2f(s) + emit2;
    float mg = grp16_max(g);
    if (valid) { aRel = g - mg; M = M + mg; }
}

// ---------- kernel 0: pack B fragments (bf16, MFMA lane order) + base ----------
// bpack flat [k=0..2][lane=0..63][j=0..7] bf16; B[kk][h] = logit2(py[h][kk]), kk>=88 -> 0
__global__ void hmm_prep(const float* __restrict__ probs_y,
                         ushort* __restrict__ bpack, float* __restrict__ base) {
    int tid = threadIdx.x;
    for (int i = tid; i < 3 * 64 * 8; i += 256) {
        int k = i >> 9;
        int l = (i >> 3) & 63;
        int j = i & 7;
        int kk = k * 32 + ((l >> 4) * 8) + j;
        int h = l & 15;
        ushort v = 0;
        if (kk < D_N) {
            float p = probs_y[h * D_N + kk];
            float lw = log2f(p) - log2f(1.0f - p);
            unsigned u = __float_as_uint(lw);
            u += 0x7FFFu + ((u >> 16) & 1u);   // RNE to bf16
            v = (ushort)(u >> 16);
        }
        bpack[i] = v;
    }
    if (tid < H_N) {
        float s = 0.0f;
        for (int d = 0; d < D_N; ++d)
            s += log2f(1.0f - probs_y[tid * D_N + d]);
        base[tid] = s;
    }
}

// ---------- kernel 1: MFMA emission; stores centered ec[B][H][T] + c[B][T] ----------
__global__ __launch_bounds__(256) void hmm_emit(
    const float* __restrict__ seq, const int* __restrict__ lengths,
    const ushort* __restrict__ bpack, const float* __restrict__ base,
    float* __restrict__ ecBuf, float* __restrict__ cBuf) {
    int bid = blockIdx.x;
    int b = bid >> 3;
    int t0 = (bid & 7) * 64;
    if (t0 >= lengths[b]) return;               // block-uniform early exit

    // seq tile as bf16, row stride 104 (208 B): 2-way LDS access = free
    __shared__ ushort sA[64 * 104];
    int tid = threadIdx.x;
    const float* gseq = seq + ((size_t)b * T_N + t0) * D_N;

    for (int f = tid; f < 768; f += 256) {
        if (f < 704) {                           // 64 rows x 11 chunks of 8 f32
            int r = f / 11;
            int c = f - r * 11;
            const float* gp = gseq + f * 8;      // f*8 == r*88 + c*8
            float4 v0 = *(const float4*)(gp);
            float4 v1 = *(const float4*)(gp + 4);
            uint4 w;
            w.x = (__float_as_uint(v0.x) >> 16) | (__float_as_uint(v0.y) & 0xFFFF0000u);
            w.y = (__float_as_uint(v0.z) >> 16) | (__float_as_uint(v0.w) & 0xFFFF0000u);
            w.z = (__float_as_uint(v1.x) >> 16) | (__float_as_uint(v1.y) & 0xFFFF0000u);
            w.w = (__float_as_uint(v1.z) >> 16) | (__float_as_uint(v1.w) & 0xFFFF0000u);
            *(uint4*)(&sA[r * 104 + c * 8]) = w;
        } else {                                 // zero k-pad 88..95 (NaN-safe)
            int r = f - 704;
            uint4 z; z.x = 0; z.y = 0; z.z = 0; z.w = 0;
            *(uint4*)(&sA[r * 104 + 88]) = z;
        }
    }
    __syncthreads();

    int l = tid & 63, w = tid >> 6;
    int q = l >> 4, h = l & 15;

    const short8* bp = (const short8*)bpack;     // same for all waves, coalesced
    short8 bf0 = bp[l];
    short8 bf1 = bp[64 + l];
    short8 bf2 = bp[128 + l];

    int arow = w * 16 + h;                       // A: m = lane&15, k = q*8+j (+32k)
    short8 af0 = *(const short8*)&sA[arow * 104 + 0  + q * 8];
    short8 af1 = *(const short8*)&sA[arow * 104 + 32 + q * 8];
    short8 af2 = *(const short8*)&sA[arow * 104 + 64 + q * 8];

    floatx4 acc = {0.f, 0.f, 0.f, 0.f};
    acc = __builtin_amdgcn_mfma_f32_16x16x32_bf16(af0, bf0, acc, 0, 0, 0);
    acc = __builtin_amdgcn_mfma_f32_16x16x32_bf16(af1, bf1, acc, 0, 0, 0);
    acc = __builtin_amdgcn_mfma_f32_16x16x32_bf16(af2, bf2, acc, 0, 0, 0);

    // C/D: col h = lane&15, row = q*4 + reg  (16 h of a row live in one DPP row)
    float bh = base[h];
    float e0 = acc[0] + bh, e1 = acc[1] + bh, e2 = acc[2] + bh, e3 = acc[3] + bh;
    float c0 = grp16_max(e0), c1 = grp16_max(e1);
    float c2 = grp16_max(e2), c3 = grp16_max(e3);

    int tloc = t0 + w * 16 + q * 4;
    float4 ecv; ecv.x = e0 - c0; ecv.y = e1 - c1; ecv.z = e2 - c2; ecv.w = e3 - c3;
    *(float4*)&ecBuf[((size_t)(b * H_N + h)) * T_N + tloc] = ecv;
    if (h == 0) {
        float4 cv; cv.x = c0; cv.y = c1; cv.z = c2; cv.w = c3;
        *(float4*)&cBuf[(size_t)b * T_N + tloc] = cv;
    }
}

// ---------- kernel 2: forward scan, 1 wave = 4 sequences, renorm per chunk ----------
__global__ __launch_bounds__(64) void hmm_scan(
    const float* __restrict__ probs_x, const float* __restrict__ ecBuf,
    const float* __restrict__ cBuf, const int* __restrict__ lengths,
    const float* __restrict__ scale, float* __restrict__ out) {
    int lane = threadIdx.x;
    int sl = lane >> 4, h = lane & 15;
    int b0 = blockIdx.x * 4;
    int b = b0 + sl;
    int len = lengths[b];

    float aro[16];
    calib(probs_x, h, aro);

    int wmax = max(max(lengths[b0], lengths[b0 + 1]),
                   max(lengths[b0 + 2], lengths[b0 + 3]));

    const float4* eb = (const float4*)(ecBuf + ((size_t)(b * H_N + h)) * T_N);
    const float4* cb = (const float4*)(cBuf + (size_t)b * T_N);
    float aRel = (h == 0) ? 0.0f : NEGF;
    float M = 0.0f;

    int nch = (wmax + 3) >> 2;
    float4 e0 = eb[0], e1 = eb[1];               // 2-chunk-deep prefetch
    float4 g0 = cb[0], g1 = cb[1];
    for (int c = 0; c < nch; ++c) {
        float4 e2 = eb[c + 2];                   // ws slack covers tiny overrun
        float4 g2 = cb[c + 2];
        int t0c = c * 4;
        scan_step(aRel, M, e0.x, g0.x, t0c + 0 < len, aro);
        scan_step(aRel, M, e0.y, g0.y, t0c + 1 < len, aro);
        scan_step(aRel, M, e0.z, g0.z, t0c + 2 < len, aro);
        scan_step(aRel, M, e0.w, g0.w, t0c + 3 < len, aro);
        float mg = grp16_max(aRel);              // representation-only: mask-free
        aRel -= mg; M += mg;
        e0 = e1; e1 = e2; g0 = g1; g1 = g2;
    }
    float pf = exp2f(aRel);
    float s = grp16_sum(pf);
    if (h == 0)
        out[b] = scale[0] * (LN2F * (M + __log2f(s)));
}

// ---------- fallback: fused naive (if ws too small) ----------
__global__ __launch_bounds__(64) void hmm_fused_naive(
    const float* __restrict__ seq, const float* __restrict__ px,
    const float* __restrict__ py, const float* __restrict__ sc,
    const int* __restrict__ lengths, float* __restrict__ out) {
    int lane = threadIdx.x;
    int sl = lane >> 4, h = lane & 15;
    int b0 = blockIdx.x * 4;
    int b = b0 + sl;
    int len = lengths[b];

    float aro[16];
    calib(px, h, aro);

    float wreg[88];
    float b2 = 0.0f;
#pragma unroll
    for (int d = 0; d < D_N; ++d) {
        float p = py[h * D_N + d];
        float l1 = log2f(1.0f - p);
        wreg[d] = log2f(p) - l1;
        b2 += l1;
    }
    int wmax = max(max(lengths[b0], lengths[b0 + 1]),
                   max(lengths[b0 + 2], lengths[b0 + 3]));

    float aRel = (h == 0) ? 0.0f : NEGF;
    float M = 0.0f;
    for (int t = 0; t < wmax; ++t) {
        const float4* sp = (const float4*)(seq + ((size_t)b * T_N + t) * D_N);
        float e = b2;
#pragma unroll
        for (int j = 0; j < 22; ++j) {
            float4 v = sp[j];
            e += v.x * wreg[4 * j] + v.y * wreg[4 * j + 1] +
                 v.z * wreg[4 * j + 2] + v.w * wreg[4 * j + 3];
        }
        hmm_step(aRel, M, e, t < len, aro);
    }
    float pf = exp2f(aRel);
    float s = grp16_sum(pf);
    if (h == 0)
        out[b] = sc[0] * (LN2F * (M + __log2f(s)));
}

extern "C" void kernel_launch(void* const* d_in, const int* in_sizes, int n_in,
                              void* d_out, int out_size, void* d_ws,
                              size_t ws_size, hipStream_t stream) {
    const float* seq = (const float*)d_in[0];   // [B,T,D] f32
    const float* px  = (const float*)d_in[1];   // [H,H]   f32 (linear probs)
    const float* py  = (const float*)d_in[2];   // [H,D]   f32
    const float* sc  = (const float*)d_in[3];   // [1]     f32
    const int*   len = (const int*)d_in[4];     // [B]     i32
    float* out = (float*)d_out;                 // [B]     f32

    size_t ec_elems = (size_t)B_N * H_N * T_N;  // 16.7M floats
    size_t c_elems  = (size_t)B_N * T_N;        // 1.05M floats
    size_t need = (ec_elems + c_elems + 16) * sizeof(float) + 1536 * sizeof(ushort);
    if (ws_size >= need) {
        float*  ecBuf = (float*)d_ws;
        float*  cBuf  = ecBuf + ec_elems;
        float*  base  = cBuf + c_elems;
        ushort* bpack = (ushort*)(base + 16);   // 16B-aligned by construction
        hmm_prep<<<1, 256, 0, stream>>>(py, bpack, base);
        hmm_emit<<<B_N * 8, 256, 0, stream>>>(seq, len, bpack, base, ecBuf, cBuf);
        hmm_scan<<<B_N / 4, 64, 0, stream>>>(px, ecBuf, cBuf, len, sc, out);
    } else {
        hmm_fused_naive<<<B_N / 4, 64, 0, stream>>>(seq, px, py, sc, len, out);
    }
}

// Round 4
// 528.764 us; speedup vs baseline: 1.1461x; 1.0315x over previous
//
#include <hip/hip_runtime.h>

#define B_N 2048
#define T_N 512
#define D_N 88
#define H_N 16
#define NEGF (-1e30f)
#define LN2F 0.69314718055994530942f

typedef __attribute__((ext_vector_type(8))) short short8;
typedef __attribute__((ext_vector_type(4))) float floatx4;

// ---------- DPP helpers (row_ror within 16-lane rows) ----------
template<int CTRL>
__device__ __forceinline__ float dppf(float x) {
    return __int_as_float(__builtin_amdgcn_update_dpp(
        0, __float_as_int(x), CTRL, 0xF, 0xF, false));
}

__device__ __forceinline__ float grp16_max(float v) {
    v = fmaxf(v, dppf<0x128>(v)); // ror8
    v = fmaxf(v, dppf<0x124>(v)); // ror4
    v = fmaxf(v, dppf<0x122>(v)); // ror2
    v = fmaxf(v, dppf<0x121>(v)); // ror1
    return v;
}
__device__ __forceinline__ float grp16_sum(float v) {
    v += dppf<0x128>(v);
    v += dppf<0x124>(v);
    v += dppf<0x122>(v);
    v += dppf<0x121>(v);
    return v;
}

__device__ __forceinline__ ushort bf16rne(float f) {
    unsigned u = __float_as_uint(f);
    u += 0x7FFFu + ((u >> 16) & 1u);
    return (ushort)(u >> 16);
}

// Self-calibrating A gather: aro[j] = A[src_lane_of_ror_j][h]
__device__ __forceinline__ void calib(const float* __restrict__ px, int h,
                                      float (&aro)[16]) {
    float idxf = (float)h;
    aro[0]  = px[h * 16 + h];
    aro[1]  = px[((int)dppf<0x121>(idxf)) * 16 + h];
    aro[2]  = px[((int)dppf<0x122>(idxf)) * 16 + h];
    aro[3]  = px[((int)dppf<0x123>(idxf)) * 16 + h];
    aro[4]  = px[((int)dppf<0x124>(idxf)) * 16 + h];
    aro[5]  = px[((int)dppf<0x125>(idxf)) * 16 + h];
    aro[6]  = px[((int)dppf<0x126>(idxf)) * 16 + h];
    aro[7]  = px[((int)dppf<0x127>(idxf)) * 16 + h];
    aro[8]  = px[((int)dppf<0x128>(idxf)) * 16 + h];
    aro[9]  = px[((int)dppf<0x129>(idxf)) * 16 + h];
    aro[10] = px[((int)dppf<0x12A>(idxf)) * 16 + h];
    aro[11] = px[((int)dppf<0x12B>(idxf)) * 16 + h];
    aro[12] = px[((int)dppf<0x12C>(idxf)) * 16 + h];
    aro[13] = px[((int)dppf<0x12D>(idxf)) * 16 + h];
    aro[14] = px[((int)dppf<0x12E>(idxf)) * 16 + h];
    aro[15] = px[((int)dppf<0x12F>(idxf)) * 16 + h];
}

__device__ __forceinline__ float matvec16(float p, const float (&aro)[16]) {
    float a0 = p * aro[0];
    float a1 = dppf<0x121>(p) * aro[1];
    float a2 = dppf<0x122>(p) * aro[2];
    float a3 = dppf<0x123>(p) * aro[3];
    a0 += dppf<0x124>(p) * aro[4];
    a1 += dppf<0x125>(p) * aro[5];
    a2 += dppf<0x126>(p) * aro[6];
    a3 += dppf<0x127>(p) * aro[7];
    a0 += dppf<0x128>(p) * aro[8];
    a1 += dppf<0x129>(p) * aro[9];
    a2 += dppf<0x12A>(p) * aro[10];
    a3 += dppf<0x12B>(p) * aro[11];
    a0 += dppf<0x12C>(p) * aro[12];
    a1 += dppf<0x12D>(p) * aro[13];
    a2 += dppf<0x12E>(p) * aro[14];
    a3 += dppf<0x12F>(p) * aro[15];
    return (a0 + a1) + (a2 + a3);
}

// old-style log-domain step (fallback kernel only)
__device__ __forceinline__ void hmm_step(float& aRel, float& M, float emit2,
                                         bool valid, const float (&aro)[16]) {
    float p = exp2f(aRel);
    float s = matvec16(p, aro);
    float g = __log2f(s) + emit2;
    float mg = grp16_max(g);
    if (valid) { aRel = g - mg; M = M + mg; }
}

// ---------- kernel 0: pack B fragments (bf16, MFMA lane order) + base ----------
__global__ void hmm_prep(const float* __restrict__ probs_y,
                         ushort* __restrict__ bpack, float* __restrict__ base) {
    int tid = threadIdx.x;
    for (int i = tid; i < 3 * 64 * 8; i += 256) {
        int k = i >> 9;
        int l = (i >> 3) & 63;
        int j = i & 7;
        int kk = k * 32 + ((l >> 4) * 8) + j;
        int h = l & 15;
        ushort v = 0;
        if (kk < D_N) {
            float p = probs_y[h * D_N + kk];
            v = bf16rne(log2f(p) - log2f(1.0f - p));
        }
        bpack[i] = v;
    }
    if (tid < H_N) {
        float s = 0.0f;
        for (int d = 0; d < D_N; ++d)
            s += log2f(1.0f - probs_y[tid * D_N + d]);
        base[tid] = s;
    }
}

// ---------- kernel 1: MFMA emission; stores w=exp2(e-c) bf16 + c f32 ----------
__global__ __launch_bounds__(256) void hmm_emit(
    const float* __restrict__ seq, const int* __restrict__ lengths,
    const ushort* __restrict__ bpack, const float* __restrict__ base,
    ushort* __restrict__ wBuf, float* __restrict__ cBuf) {
    int bid = blockIdx.x;
    int b = bid >> 3;
    int t0 = (bid & 7) * 64;
    if (t0 >= lengths[b]) return;               // block-uniform early exit

    // seq tile as bf16, row stride 104 (208 B): 2-way LDS access = free
    __shared__ ushort sA[64 * 104];
    int tid = threadIdx.x;
    const float* gseq = seq + ((size_t)b * T_N + t0) * D_N;

    for (int f = tid; f < 768; f += 256) {
        if (f < 704) {                           // 64 rows x 11 chunks of 8 f32
            int r = f / 11;
            int c = f - r * 11;
            const float* gp = gseq + f * 8;      // f*8 == r*88 + c*8
            float4 v0 = *(const float4*)(gp);
            float4 v1 = *(const float4*)(gp + 4);
            uint4 w;
            w.x = (__float_as_uint(v0.x) >> 16) | (__float_as_uint(v0.y) & 0xFFFF0000u);
            w.y = (__float_as_uint(v0.z) >> 16) | (__float_as_uint(v0.w) & 0xFFFF0000u);
            w.z = (__float_as_uint(v1.x) >> 16) | (__float_as_uint(v1.y) & 0xFFFF0000u);
            w.w = (__float_as_uint(v1.z) >> 16) | (__float_as_uint(v1.w) & 0xFFFF0000u);
            *(uint4*)(&sA[r * 104 + c * 8]) = w;
        } else {                                 // zero k-pad 88..95 (NaN-safe)
            int r = f - 704;
            uint4 z; z.x = 0; z.y = 0; z.z = 0; z.w = 0;
            *(uint4*)(&sA[r * 104 + 88]) = z;
        }
    }
    __syncthreads();

    int l = tid & 63, w = tid >> 6;
    int q = l >> 4, h = l & 15;

    const short8* bp = (const short8*)bpack;     // wave-uniform, L2-resident
    short8 bf0 = bp[l];
    short8 bf1 = bp[64 + l];
    short8 bf2 = bp[128 + l];

    int arow = w * 16 + h;                       // A: m = lane&15, k = q*8+j (+32k)
    short8 af0 = *(const short8*)&sA[arow * 104 + 0  + q * 8];
    short8 af1 = *(const short8*)&sA[arow * 104 + 32 + q * 8];
    short8 af2 = *(const short8*)&sA[arow * 104 + 64 + q * 8];

    floatx4 acc = {0.f, 0.f, 0.f, 0.f};
    acc = __builtin_amdgcn_mfma_f32_16x16x32_bf16(af0, bf0, acc, 0, 0, 0);
    acc = __builtin_amdgcn_mfma_f32_16x16x32_bf16(af1, bf1, acc, 0, 0, 0);
    acc = __builtin_amdgcn_mfma_f32_16x16x32_bf16(af2, bf2, acc, 0, 0, 0);

    // C/D: col h = lane&15, row = q*4 + reg  (16 h of a row live in one DPP row)
    float bh = base[h];
    float e0 = acc[0] + bh, e1 = acc[1] + bh, e2 = acc[2] + bh, e3 = acc[3] + bh;
    float c0 = grp16_max(e0), c1 = grp16_max(e1);
    float c2 = grp16_max(e2), c3 = grp16_max(e3);

    int tloc = t0 + w * 16 + q * 4;
    ushort4 wv;
    wv.x = bf16rne(exp2f(e0 - c0));
    wv.y = bf16rne(exp2f(e1 - c1));
    wv.z = bf16rne(exp2f(e2 - c2));
    wv.w = bf16rne(exp2f(e3 - c3));
    *(ushort4*)&wBuf[((size_t)(b * H_N + h)) * T_N + tloc] = wv;
    if (h == 0) {
        float4 cv; cv.x = c0; cv.y = c1; cv.z = c2; cv.w = c3;
        *(float4*)&cBuf[(size_t)b * T_N + tloc] = cv;
    }
}

// ---------- kernel 2: linear-domain scan, 1 wave = 4 sequences ----------
__global__ __launch_bounds__(64) void hmm_scan(
    const float* __restrict__ probs_x, const ushort* __restrict__ wBuf,
    const float* __restrict__ cBuf, const int* __restrict__ lengths,
    const float* __restrict__ scale, float* __restrict__ out) {
    int lane = threadIdx.x;
    int sl = lane >> 4, h = lane & 15;
    int b0 = blockIdx.x * 4;
    int b = b0 + sl;
    int len = lengths[b];

    float aro[16];
    calib(probs_x, h, aro);                      // linear A

    int wmax = max(max(lengths[b0], lengths[b0 + 1]),
                   max(lengths[b0 + 2], lengths[b0 + 3]));

    const ushort4* eb = (const ushort4*)(wBuf + ((size_t)(b * H_N + h)) * T_N);
    const float4*  cb = (const float4*)(cBuf + (size_t)b * T_N);
    float aLin = (h == 0) ? 1.0f : 0.0f;         // alpha0 = delta at state 0
    float M = 0.0f;                              // alpha = aLin * 2^M (per group)

    int nch = (wmax + 3) >> 2;
    ushort4 wA = eb[0], wB = eb[1], wC = eb[2];  // 3-chunk-deep prefetch
    float4  cA = cb[0], cB = cb[1], cC = cb[2];
    for (int c = 0; c < nch; ++c) {
        ushort4 wD = eb[c + 3];                  // ws slack covers tiny overrun
        float4  cD = cb[c + 3];
        float f0 = __uint_as_float((unsigned)wA.x << 16);
        float f1 = __uint_as_float((unsigned)wA.y << 16);
        float f2 = __uint_as_float((unsigned)wA.z << 16);
        float f3 = __uint_as_float((unsigned)wA.w << 16);
        int t0c = c * 4;
        float s;
        s = matvec16(aLin, aro); if (t0c + 0 < len) { aLin = s * f0; M += cA.x; }
        s = matvec16(aLin, aro); if (t0c + 1 < len) { aLin = s * f1; M += cA.y; }
        s = matvec16(aLin, aro); if (t0c + 2 < len) { aLin = s * f2; M += cA.z; }
        s = matvec16(aLin, aro); if (t0c + 3 < len) { aLin = s * f3; M += cA.w; }
        // exact power-of-2 renorm (representation-only; mask-free)
        float mx = grp16_max(aLin);
        unsigned ex = (__float_as_uint(mx) >> 23) & 0xFFu;
        aLin *= __uint_as_float((254u - ex) << 23);   // * 2^(127-E)
        M += (float)((int)ex - 127);
        wA = wB; wB = wC; wC = wD;
        cA = cB; cB = cC; cC = cD;
    }
    float ssum = grp16_sum(aLin);
    if (h == 0)
        out[b] = scale[0] * (LN2F * (M + __log2f(ssum)));
}

// ---------- fallback: fused naive (if ws too small) ----------
__global__ __launch_bounds__(64) void hmm_fused_naive(
    const float* __restrict__ seq, const float* __restrict__ px,
    const float* __restrict__ py, const float* __restrict__ sc,
    const int* __restrict__ lengths, float* __restrict__ out) {
    int lane = threadIdx.x;
    int sl = lane >> 4, h = lane & 15;
    int b0 = blockIdx.x * 4;
    int b = b0 + sl;
    int len = lengths[b];

    float aro[16];
    calib(px, h, aro);

    float wreg[88];
    float b2 = 0.0f;
#pragma unroll
    for (int d = 0; d < D_N; ++d) {
        float p = py[h * D_N + d];
        float l1 = log2f(1.0f - p);
        wreg[d] = log2f(p) - l1;
        b2 += l1;
    }
    int wmax = max(max(lengths[b0], lengths[b0 + 1]),
                   max(lengths[b0 + 2], lengths[b0 + 3]));

    float aRel = (h == 0) ? 0.0f : NEGF;
    float M = 0.0f;
    for (int t = 0; t < wmax; ++t) {
        const float4* sp = (const float4*)(seq + ((size_t)b * T_N + t) * D_N);
        float e = b2;
#pragma unroll
        for (int j = 0; j < 22; ++j) {
            float4 v = sp[j];
            e += v.x * wreg[4 * j] + v.y * wreg[4 * j + 1] +
                 v.z * wreg[4 * j + 2] + v.w * wreg[4 * j + 3];
        }
        hmm_step(aRel, M, e, t < len, aro);
    }
    float pf = exp2f(aRel);
    float s = grp16_sum(pf);
    if (h == 0)
        out[b] = sc[0] * (LN2F * (M + __log2f(s)));
}

extern "C" void kernel_launch(void* const* d_in, const int* in_sizes, int n_in,
                              void* d_out, int out_size, void* d_ws,
                              size_t ws_size, hipStream_t stream) {
    const float* seq = (const float*)d_in[0];   // [B,T,D] f32
    const float* px  = (const float*)d_in[1];   // [H,H]   f32 (linear probs)
    const float* py  = (const float*)d_in[2];   // [H,D]   f32
    const float* sc  = (const float*)d_in[3];   // [1]     f32
    const int*   len = (const int*)d_in[4];     // [B]     i32
    float* out = (float*)d_out;                 // [B]     f32

    size_t w_elems = (size_t)B_N * H_N * T_N;   // 16.7M ushorts (33.5 MB)
    size_t c_elems = (size_t)B_N * T_N;         // 1.05M floats
    size_t need = w_elems * 2 + c_elems * 4 + 16 * 4 + 1536 * 2 + 256;
    if (ws_size >= need) {
        ushort* wBuf  = (ushort*)d_ws;
        float*  cBuf  = (float*)(wBuf + w_elems);
        float*  base  = cBuf + c_elems;
        ushort* bpack = (ushort*)(base + 16);
        hmm_prep<<<1, 256, 0, stream>>>(py, bpack, base);
        hmm_emit<<<B_N * 8, 256, 0, stream>>>(seq, len, bpack, base, wBuf, cBuf);
        hmm_scan<<<B_N / 4, 64, 0, stream>>>(px, wBuf, cBuf, len, sc, out);
    } else {
        hmm_fused_naive<<<B_N / 4, 64, 0, stream>>>(seq, px, py, sc, len, out);
    }
}

// Round 6
// 522.209 us; speedup vs baseline: 1.1605x; 1.0126x over previous
//
#include <hip/hip_runtime.h>

#define B_N 2048
#define T_N 512
#define D_N 88
#define H_N 16
#define NEGF (-1e30f)
#define LN2F 0.69314718055994530942f

typedef __attribute__((ext_vector_type(8))) short short8;
typedef __attribute__((ext_vector_type(4))) short short4v;
typedef __attribute__((ext_vector_type(4))) float floatx4;

// ---------- DPP helpers (row_ror within 16-lane rows) ----------
template<int CTRL>
__device__ __forceinline__ float dppf(float x) {
    return __int_as_float(__builtin_amdgcn_update_dpp(
        0, __float_as_int(x), CTRL, 0xF, 0xF, false));
}

__device__ __forceinline__ float grp16_max(float v) {
    v = fmaxf(v, dppf<0x128>(v)); // ror8
    v = fmaxf(v, dppf<0x124>(v)); // ror4
    v = fmaxf(v, dppf<0x122>(v)); // ror2
    v = fmaxf(v, dppf<0x121>(v)); // ror1
    return v;
}
__device__ __forceinline__ float grp16_sum(float v) {
    v += dppf<0x128>(v);
    v += dppf<0x124>(v);
    v += dppf<0x122>(v);
    v += dppf<0x121>(v);
    return v;
}

__device__ __forceinline__ ushort bf16rne(float f) {
    unsigned u = __float_as_uint(f);
    u += 0x7FFFu + ((u >> 16) & 1u);
    return (ushort)(u >> 16);
}

// truncating pack of two f32 into {lo=bf16(x), hi=bf16(y)}
__device__ __forceinline__ unsigned packbf(float x, float y) {
    return (__float_as_uint(x) >> 16) | (__float_as_uint(y) & 0xFFFF0000u);
}

__device__ __forceinline__ float swz_xor16_f(float v) {
    return __int_as_float(
        __builtin_amdgcn_ds_swizzle(__float_as_int(v), 0x401F));
}

// one 16x16x16 bf16 MFMA step. Device-only conditional (no host-visible
// structure depends on __has_builtin — that divergence caused R5's abort).
__device__ __forceinline__ floatx4 mfma16(short4v a, short4v b) {
    floatx4 z = {0.f, 0.f, 0.f, 0.f};
#if __has_builtin(__builtin_amdgcn_mfma_f32_16x16x16bf16_1k)
    return __builtin_amdgcn_mfma_f32_16x16x16bf16_1k(a, b, z, 0, 0, 0);
#else
    floatx4 d;
    asm volatile("v_mfma_f32_16x16x16_bf16 %0, %1, %2, %3\n\t"
                 "s_nop 7\n\ts_nop 7"
                 : "=&v"(d) : "v"(a), "v"(b), "v"(z));
    return d;
#endif
}

// Self-calibrating A gather (fused-naive fallback only)
__device__ __forceinline__ void calib(const float* __restrict__ px, int h,
                                      float (&aro)[16]) {
    float idxf = (float)h;
    aro[0]  = px[h * 16 + h];
    aro[1]  = px[((int)dppf<0x121>(idxf)) * 16 + h];
    aro[2]  = px[((int)dppf<0x122>(idxf)) * 16 + h];
    aro[3]  = px[((int)dppf<0x123>(idxf)) * 16 + h];
    aro[4]  = px[((int)dppf<0x124>(idxf)) * 16 + h];
    aro[5]  = px[((int)dppf<0x125>(idxf)) * 16 + h];
    aro[6]  = px[((int)dppf<0x126>(idxf)) * 16 + h];
    aro[7]  = px[((int)dppf<0x127>(idxf)) * 16 + h];
    aro[8]  = px[((int)dppf<0x128>(idxf)) * 16 + h];
    aro[9]  = px[((int)dppf<0x129>(idxf)) * 16 + h];
    aro[10] = px[((int)dppf<0x12A>(idxf)) * 16 + h];
    aro[11] = px[((int)dppf<0x12B>(idxf)) * 16 + h];
    aro[12] = px[((int)dppf<0x12C>(idxf)) * 16 + h];
    aro[13] = px[((int)dppf<0x12D>(idxf)) * 16 + h];
    aro[14] = px[((int)dppf<0x12E>(idxf)) * 16 + h];
    aro[15] = px[((int)dppf<0x12F>(idxf)) * 16 + h];
}

__device__ __forceinline__ float matvec16(float p, const float (&aro)[16]) {
    float a0 = p * aro[0];
    float a1 = dppf<0x121>(p) * aro[1];
    float a2 = dppf<0x122>(p) * aro[2];
    float a3 = dppf<0x123>(p) * aro[3];
    a0 += dppf<0x124>(p) * aro[4];
    a1 += dppf<0x125>(p) * aro[5];
    a2 += dppf<0x126>(p) * aro[6];
    a3 += dppf<0x127>(p) * aro[7];
    a0 += dppf<0x128>(p) * aro[8];
    a1 += dppf<0x129>(p) * aro[9];
    a2 += dppf<0x12A>(p) * aro[10];
    a3 += dppf<0x12B>(p) * aro[11];
    a0 += dppf<0x12C>(p) * aro[12];
    a1 += dppf<0x12D>(p) * aro[13];
    a2 += dppf<0x12E>(p) * aro[14];
    a3 += dppf<0x12F>(p) * aro[15];
    return (a0 + a1) + (a2 + a3);
}

// log-domain step (fused-naive fallback only)
__device__ __forceinline__ void hmm_step(float& aRel, float& M, float emit2,
                                         bool valid, const float (&aro)[16]) {
    float p = exp2f(aRel);
    float s = matvec16(p, aro);
    float g = __log2f(s) + emit2;
    float mg = grp16_max(g);
    if (valid) { aRel = g - mg; M = M + mg; }
}

// ---------- kernel 0: pack B fragments + base + zero cSum ----------
__global__ void hmm_prep(const float* __restrict__ probs_y,
                         ushort* __restrict__ bpack, float* __restrict__ base,
                         float* __restrict__ cSum) {
    int tid = threadIdx.x;
    for (int i = tid; i < 3 * 64 * 8; i += 256) {
        int k = i >> 9;
        int l = (i >> 3) & 63;
        int j = i & 7;
        int kk = k * 32 + ((l >> 4) * 8) + j;
        int h = l & 15;
        ushort v = 0;
        if (kk < D_N) {
            float p = probs_y[h * D_N + kk];
            v = bf16rne(log2f(p) - log2f(1.0f - p));
        }
        bpack[i] = v;
    }
    for (int i = tid; i < B_N; i += 256) cSum[i] = 0.0f;
    if (tid < H_N) {
        float s = 0.0f;
        for (int d = 0; d < D_N; ++d)
            s += log2f(1.0f - probs_y[tid * D_N + d]);
        base[tid] = s;
    }
}

// ---------- kernel 1: MFMA emission; w=exp2(e-c) bf16 [b][t][h] + csum ----------
__global__ __launch_bounds__(256) void hmm_emit(
    const float* __restrict__ seq, const int* __restrict__ lengths,
    const ushort* __restrict__ bpack, const float* __restrict__ base,
    ushort* __restrict__ wBuf, float* __restrict__ cSum) {
    int bid = blockIdx.x;
    int b = bid >> 3;
    int t0 = (bid & 7) * 64;
    int len = lengths[b];
    if (t0 >= len) return;                      // block-uniform early exit
    int lenLoc = min(len - t0, 64);             // live rows in this tile

    __shared__ ushort sA[64 * 104];             // bf16 rows, stride 104
    int tid = threadIdx.x;
    const float* gseq = seq + ((size_t)b * T_N + t0) * D_N;

    for (int f = tid; f < 768; f += 256) {
        if (f < 704) {                           // 64 rows x 11 chunks of 8 f32
            int r = f / 11;
            if (r < lenLoc) {                    // skip dead rows: saves HBM
                int c = f - r * 11;
                const float* gp = gseq + f * 8;  // f*8 == r*88 + c*8
                float4 v0 = *(const float4*)(gp);
                float4 v1 = *(const float4*)(gp + 4);
                uint4 w;
                w.x = (__float_as_uint(v0.x) >> 16) | (__float_as_uint(v0.y) & 0xFFFF0000u);
                w.y = (__float_as_uint(v0.z) >> 16) | (__float_as_uint(v0.w) & 0xFFFF0000u);
                w.z = (__float_as_uint(v1.x) >> 16) | (__float_as_uint(v1.y) & 0xFFFF0000u);
                w.w = (__float_as_uint(v1.z) >> 16) | (__float_as_uint(v1.w) & 0xFFFF0000u);
                *(uint4*)(&sA[r * 104 + c * 8]) = w;
            }
        } else {                                 // zero k-pad 88..95
            int r = f - 704;
            uint4 z; z.x = 0; z.y = 0; z.z = 0; z.w = 0;
            *(uint4*)(&sA[r * 104 + 88]) = z;
        }
    }
    __syncthreads();

    int l = tid & 63, w = tid >> 6;
    int q = l >> 4, h = l & 15;

    const short8* bp = (const short8*)bpack;
    short8 bf0 = bp[l];
    short8 bf1 = bp[64 + l];
    short8 bf2 = bp[128 + l];

    int arow = w * 16 + h;
    short8 af0 = *(const short8*)&sA[arow * 104 + 0  + q * 8];
    short8 af1 = *(const short8*)&sA[arow * 104 + 32 + q * 8];
    short8 af2 = *(const short8*)&sA[arow * 104 + 64 + q * 8];

    floatx4 acc = {0.f, 0.f, 0.f, 0.f};
    acc = __builtin_amdgcn_mfma_f32_16x16x32_bf16(af0, bf0, acc, 0, 0, 0);
    acc = __builtin_amdgcn_mfma_f32_16x16x32_bf16(af1, bf1, acc, 0, 0, 0);
    acc = __builtin_amdgcn_mfma_f32_16x16x32_bf16(af2, bf2, acc, 0, 0, 0);

    // C/D: col h = lane&15, row = q*4 + reg
    float bh = base[h];
    float e0 = acc[0] + bh, e1 = acc[1] + bh, e2 = acc[2] + bh, e3 = acc[3] + bh;
    float c0 = grp16_max(e0), c1 = grp16_max(e1);
    float c2 = grp16_max(e2), c3 = grp16_max(e3);

    int tRow = t0 + w * 16 + q * 4;
    // layout [b][t][h] for the MFMA scan (unconditional)
    size_t wb = ((size_t)b * T_N + tRow) * H_N + h;
    wBuf[wb]      = bf16rne(exp2f(e0 - c0));
    wBuf[wb + 16] = bf16rne(exp2f(e1 - c1));
    wBuf[wb + 32] = bf16rne(exp2f(e2 - c2));
    wBuf[wb + 48] = bf16rne(exp2f(e3 - c3));

    // csum: masked sum of c over this wave's 16 rows, one atomic per wave
    float cs = 0.0f;
    if (tRow + 0 < len) cs += c0;
    if (tRow + 1 < len) cs += c1;
    if (tRow + 2 < len) cs += c2;
    if (tRow + 3 < len) cs += c3;
    cs += swz_xor16_f(cs);
    cs += __shfl_xor(cs, 32, 64);
    if (l == 0) atomicAdd(&cSum[b], cs);
}

// ---------- kernel 2: MFMA forward scan, 1 wave = 16 sequences ----------
// alpha held as 16x16 [state][seq] in MFMA C-layout; closure: C-layout == B-layout.
// Renorm/M/tot reductions are over lanes {s, s+16, s+32, s+48} = PER-SEQ.
__global__ __launch_bounds__(64) void hmm_scan_mfma(
    const float* __restrict__ px, const ushort* __restrict__ wBuf,
    const float* __restrict__ cSum, const int* __restrict__ lengths,
    const float* __restrict__ scale, float* __restrict__ out) {
    int lane = threadIdx.x;
    int s = lane & 15, q = lane >> 4;
    int b0 = blockIdx.x * 16;
    int b = b0 + s;
    int len = lengths[b];
    int wmax = (int)__builtin_amdgcn_readfirstlane(grp16_max((float)len));

    // A-operand: Aop[m=lane&15][k=q*4+j] = A[k][m]  (transition k -> m)
    short4v af;
#pragma unroll
    for (int j = 0; j < 4; ++j)
        af[j] = (short)bf16rne(px[(q * 4 + j) * 16 + (lane & 15)]);

    // alpha: a_j = alpha[row=q*4+j][col=s]; init delta at state 0
    float a0 = (q == 0) ? 1.0f : 0.0f, a1 = 0.f, a2 = 0.f, a3 = 0.f;
    unsigned bp0 = packbf(a0, a1), bp1 = packbf(a2, a3);

    float fin = 0.f, finM = 0.f, M = 0.f;
    float S = 1.0f, Epend = 0.0f;                // per-seq lagged renorm

    const ushort4* wp = (const ushort4*)wBuf;    // [b][t][q] as ushort4
    size_t idx0 = (size_t)b * (T_N * 4) + q;

    ushort4 rA[8], rB[8];
#pragma unroll
    for (int j = 0; j < 8; ++j) rA[j] = wp[idx0 + (size_t)j * 4];

    int ngrp = (wmax + 7) >> 3;
    for (int g = 0; g < ngrp; ++g) {
        int tg = g * 8;
#pragma unroll
        for (int j = 0; j < 8; ++j)              // prefetch next group
            rB[j] = wp[idx0 + (size_t)(tg + 8 + j) * 4];
#pragma unroll
        for (int j = 0; j < 8; ++j) {
            ushort4 w4 = rA[j];
            float w0 = __uint_as_float((unsigned)w4.x << 16);
            float w1 = __uint_as_float((unsigned)w4.y << 16);
            float w2 = __uint_as_float((unsigned)w4.z << 16);
            float w3 = __uint_as_float((unsigned)w4.w << 16);
            if (j == 1) {                        // apply lagged per-seq renorm
                w0 *= S; w1 *= S; w2 *= S; w3 *= S;
                M += Epend;
            }
            union { unsigned u[2]; short4v v; } bu;
            bu.u[0] = bp0; bu.u[1] = bp1;
            floatx4 d = mfma16(af, bu.v);
            a0 = d[0] * w0; a1 = d[1] * w1; a2 = d[2] * w2; a3 = d[3] * w3;
            bp0 = packbf(a0, a1); bp1 = packbf(a2, a3);
            int t = tg + j;
            bool snap = (t == len - 1);          // capture alpha at t=len-1
            float s4 = (a0 + a1) + (a2 + a3);
            fin  = snap ? s4 : fin;
            finM = snap ? M : finM;
            if (j == 7) {                        // renorm factor (used at j==1)
                float mx = fmaxf(fmaxf(a0, a1), fmaxf(a2, a3));
                mx = fmaxf(mx, swz_xor16_f(mx));          // xor lane-bit 4
                mx = fmaxf(mx, __shfl_xor(mx, 32, 64));   // xor lane-bit 5
                unsigned ex = (__float_as_uint(mx) >> 23) & 0xFFu;
                S = __uint_as_float((254u - ex) << 23);   // 2^(127-E)
                Epend = (float)((int)ex - 127);
            }
        }
#pragma unroll
        for (int j = 0; j < 8; ++j) rA[j] = rB[j];
    }
    float tot = fin;                             // sum over 16 states of seq s
    tot += swz_xor16_f(tot);
    tot += __shfl_xor(tot, 32, 64);
    float ll = LN2F * (cSum[b] + finM + __log2f(tot));
    if (lane < 16) out[b] = scale[0] * ll;
}

// ---------- fallback: fused naive (if ws too small) ----------
__global__ __launch_bounds__(64) void hmm_fused_naive(
    const float* __restrict__ seq, const float* __restrict__ px,
    const float* __restrict__ py, const float* __restrict__ sc,
    const int* __restrict__ lengths, float* __restrict__ out) {
    int lane = threadIdx.x;
    int sl = lane >> 4, h = lane & 15;
    int b0 = blockIdx.x * 4;
    int b = b0 + sl;
    int len = lengths[b];

    float aro[16];
    calib(px, h, aro);

    float wreg[88];
    float b2 = 0.0f;
#pragma unroll
    for (int d = 0; d < D_N; ++d) {
        float p = py[h * D_N + d];
        float l1 = log2f(1.0f - p);
        wreg[d] = log2f(p) - l1;
        b2 += l1;
    }
    int wmax = max(max(lengths[b0], lengths[b0 + 1]),
                   max(lengths[b0 + 2], lengths[b0 + 3]));

    float aRel = (h == 0) ? 0.0f : NEGF;
    float M = 0.0f;
    for (int t = 0; t < wmax; ++t) {
        const float4* sp = (const float4*)(seq + ((size_t)b * T_N + t) * D_N);
        float e = b2;
#pragma unroll
        for (int j = 0; j < 22; ++j) {
            float4 v = sp[j];
            e += v.x * wreg[4 * j] + v.y * wreg[4 * j + 1] +
                 v.z * wreg[4 * j + 2] + v.w * wreg[4 * j + 3];
        }
        hmm_step(aRel, M, e, t < len, aro);
    }
    float pf = exp2f(aRel);
    float s = grp16_sum(pf);
    if (h == 0)
        out[b] = sc[0] * (LN2F * (M + __log2f(s)));
}

extern "C" void kernel_launch(void* const* d_in, const int* in_sizes, int n_in,
                              void* d_out, int out_size, void* d_ws,
                              size_t ws_size, hipStream_t stream) {
    const float* seq = (const float*)d_in[0];   // [B,T,D] f32
    const float* px  = (const float*)d_in[1];   // [H,H]   f32 (linear probs)
    const float* py  = (const float*)d_in[2];   // [H,D]   f32
    const float* sc  = (const float*)d_in[3];   // [1]     f32
    const int*   len = (const int*)d_in[4];     // [B]     i32
    float* out = (float*)d_out;                 // [B]     f32

    size_t w_elems = (size_t)B_N * H_N * T_N;   // 16.7M ushorts (33.5 MB)
    size_t need = w_elems * 2 + B_N * 4 + 16 * 4 + 1536 * 2 + 4096;
    if (ws_size >= need) {
        ushort* wBuf  = (ushort*)d_ws;
        float*  cSum  = (float*)(wBuf + w_elems);
        float*  base  = cSum + B_N;
        ushort* bpack = (ushort*)(base + 16);
        hmm_prep<<<1, 256, 0, stream>>>(py, bpack, base, cSum);
        hmm_emit<<<B_N * 8, 256, 0, stream>>>(seq, len, bpack, base, wBuf, cSum);
        hmm_scan_mfma<<<B_N / 16, 64, 0, stream>>>(px, wBuf, cSum, len, sc, out);
    } else {
        hmm_fused_naive<<<B_N / 4, 64, 0, stream>>>(seq, px, py, sc, len, out);
    }
}